// Round 1
// baseline (289.262 us; speedup 1.0000x reference)
//
#include <hip/hip_runtime.h>
#include <math.h>

// tau(k) = 3.9 * kL^(-2/3) / sqrt( 2F1(1/3, 17/6, 4/3, -kL^-2) ),  kL = 0.59*|k|
// q = kL^2.  Fold q^(-1/3) into the rsqrt argument (out = 3.9*rsqrt(arg)):
//   Branch A (q >= 1/phi): arg = q * r^(1/3) * S_A,  r = 1/(1+q), S_A = 2F1(1/3,-3/2,4/3, r)
//   Branch B (q <  1/phi): arg = A*q + B*q^(7/2)*S_B, S_B = 2F1(17/6,5/2,7/2, -q)
//     q^(7/2) = q^3 * sqrt(q);  B = -2/15 exact;  A = 0.68834394
// Series args bounded by 1/phi = 0.618 -> NT=12 gives ~6e-4 relative tail.
//
// This version: block-contiguous LDS-staged loads.
//   Old pattern: per-lane 48B-stride dwordx4 loads (3x address amplification).
//   New pattern: block owns 1024 elems = 768 float4; threads load float4 at
//   block-stride 256 (unit-stride across lanes, perfectly coalesced), square,
//   stage to LDS; element read side uses dword-stride-3 (odd -> 2 lanes/bank,
//   conflict-free) with stride-256 element interleave so the 4 scalar stores
//   per thread are also perfectly coalesced per instruction.

#define NT 12

__host__ __device__ constexpr float coefA(int n) {
    // a=1/3, b=-3/2, c=4/3:  (a+n)(b+n)/((c+n)(n+1))
    return (float)(((1.0/3.0 + n) * (n - 1.5)) / ((4.0/3.0 + n) * (n + 1.0)));
}
__host__ __device__ constexpr float coefB(int n) {
    // a=17/6, b=5/2, c=7/2
    return (float)(((17.0/6.0 + n) * (n + 2.5)) / ((3.5 + n) * (n + 1.0)));
}

__device__ __forceinline__ float frcp(float x)   { return __builtin_amdgcn_rcpf(x); }
__device__ __forceinline__ float frsq(float x)   { return __builtin_amdgcn_rsqf(x); }
__device__ __forceinline__ float fsqrt_(float x) { return __builtin_amdgcn_sqrtf(x); }
#if __has_builtin(__builtin_amdgcn_logf)
__device__ __forceinline__ float flog2(float x)  { return __builtin_amdgcn_logf(x); }
#else
__device__ __forceinline__ float flog2(float x)  { return __log2f(x); }
#endif
#if __has_builtin(__builtin_amdgcn_exp2f)
__device__ __forceinline__ float fexp2(float x)  { return __builtin_amdgcn_exp2f(x); }
#else
__device__ __forceinline__ float fexp2(float x)  { return exp2f(x); }
#endif

__global__ __launch_bounds__(256) void mann_elt_kernel(
        const float* __restrict__ k, float* __restrict__ out, int n_elems) {
    // 1024 elements per block = 3072 input floats = 768 float4 = 12 KiB staged.
    __shared__ float s[3072];

    const int t     = threadIdx.x;
    const int chunk = blockIdx.x;
    const int ebase = chunk << 10;       // first element of this chunk
    const int f4base = chunk * 768;      // first input float4 of this chunk
    const int n_f4  = (3 * n_elems) >> 2;

    // ---- Stage: coalesced float4 loads (unit lane stride), square, to LDS ----
    const float4* __restrict__ k4 = (const float4*)k;
    #pragma unroll
    for (int i = 0; i < 3; ++i) {
        int idx4 = f4base + (i << 8) + t;
        float4 v = make_float4(0.f, 0.f, 0.f, 0.f);
        if (idx4 < n_f4) v = k4[idx4];
        float4 w = make_float4(v.x * v.x, v.y * v.y, v.z * v.z, v.w * v.w);
        // contiguous b128 writes across the wave: optimal 8-phase, conflict-free
        ((float4*)s)[(i << 8) + t] = w;
    }
    __syncthreads();

    // ---- Compute: 4 elements per thread, interleaved at stride 256 ----
    const float LS2 = 0.3481f;  // 0.59^2
    float q[4], z[4], acc[4], rr[4];
    bool brA[4];
    #pragma unroll
    for (int e = 0; e < 4; ++e) {
        int le = t + (e << 8);           // local element index
        // dword addr 3*le: odd stride -> 64 lanes cover 32 banks 2x -> free
        float s0 = s[3 * le + 0];
        float s1 = s[3 * le + 1];
        float s2 = s[3 * le + 2];
        q[e]   = LS2 * ((s0 + s1) + s2);
        brA[e] = q[e] >= 0.6180339887f;  // t = 1/q <= phi
        rr[e]  = frcp(1.0f + q[e]);      // = series arg for branch A
        z[e]   = brA[e] ? rr[e] : -q[e];
        acc[e] = 1.0f;
    }

    // Unified Horner; coefficients are compile-time literals, per-lane selected
    // (v_cndmask) -> no divergent loop; 4 independent dependency chains.
    #pragma unroll
    for (int n = NT - 1; n >= 0; --n) {
        const float cA = coefA(n);
        const float cB = coefB(n);
        #pragma unroll
        for (int e = 0; e < 4; ++e) {
            float c = brA[e] ? cA : cB;
            acc[e] = fmaf(c * z[e], acc[e], 1.0f);
        }
    }

    #pragma unroll
    for (int e = 0; e < 4; ++e) {
        float qq = q[e];
        float S  = acc[e];
        // Branch A: arg = q * r^(1/3) * S   (r^(1/3) via native log2/exp2)
        float cr   = fexp2(flog2(rr[e]) * (1.0f / 3.0f));
        float argA = qq * cr * S;
        // Branch B: arg = A*q + B*q^3*sqrt(q)*S   (no log/exp needed)
        float q72  = qq * qq * qq * fsqrt_(qq);
        float argB = fmaf((-2.0f / 15.0f) * q72, S, 0.68834394f * qq);
        float arg  = brA[e] ? argA : argB;
        int ge = ebase + t + (e << 8);
        // 4 scalar stores, each perfectly coalesced across the wave
        if (ge < n_elems) out[ge] = 3.9f * frsq(arg);
    }
}

extern "C" void kernel_launch(void* const* d_in, const int* in_sizes, int n_in,
                              void* d_out, int out_size, void* d_ws, size_t ws_size,
                              hipStream_t stream) {
    const float* k = (const float*)d_in[0];
    float* out = (float*)d_out;
    int n_elems = out_size;                          // 16,777,216 floats
    int blocks = (n_elems + 1023) >> 10;             // 16384 chunks of 1024
    mann_elt_kernel<<<blocks, 256, 0, stream>>>(k, out, n_elems);
}

// Round 3
// 288.988 us; speedup vs baseline: 1.0009x; 1.0009x over previous
//
#include <hip/hip_runtime.h>
#include <math.h>

// tau(k) = 3.9 * kL^(-2/3) / sqrt( 2F1(1/3, 17/6, 4/3, -kL^-2) ),  kL = 0.59*|k|
// q = kL^2.  Fold q^(-1/3) into the rsqrt argument (out = 3.9*rsqrt(arg)):
//   Branch A (q >= 1/phi): arg = q * r^(1/3) * S_A,  r = 1/(1+q), S_A = 2F1(1/3,-3/2,4/3, r)
//   Branch B (q <  1/phi): arg = A*q + B*q^(7/2)*S_B, S_B = 2F1(17/6,5/2,7/2, -q)
//     q^(7/2) = q^3 * sqrt(q);  B = -2/15 exact;  A = 0.68834394
// Series args bounded by 1/phi = 0.618 -> NT=12 gives ~6e-4 relative tail.
//
// Rocprof findings (r1): measured dur_us includes ~240us of harness
// poison-fills (2x 805MB @ 6.7TB/s); the kernel itself is ~46-49us vs a
// 268MB / 6.3TB/s = ~42.5us mixed-stream floor.  The direct 48B-stride
// dwordx4 load pattern is FINE (L1 absorbs the 3x line re-touch; TA work
// hides under wave parallelism) and beat the LDS-staged variant by ~3us.
// This version: direct loads (best known) + non-temporal stores (output is
// write-once, keep it out of L2/L3 retention against the read stream).
// r2 fix: __builtin_nontemporal_store needs a NATIVE vector type, not
// HIP_vector_type<float,4> -> use ext_vector_type(4) alias.

#define NT 12

typedef float nfloat4 __attribute__((ext_vector_type(4)));

__host__ __device__ constexpr float coefA(int n) {
    // a=1/3, b=-3/2, c=4/3:  (a+n)(b+n)/((c+n)(n+1))
    return (float)(((1.0/3.0 + n) * (n - 1.5)) / ((4.0/3.0 + n) * (n + 1.0)));
}
__host__ __device__ constexpr float coefB(int n) {
    // a=17/6, b=5/2, c=7/2
    return (float)(((17.0/6.0 + n) * (n + 2.5)) / ((3.5 + n) * (n + 1.0)));
}

__device__ __forceinline__ float frcp(float x)   { return __builtin_amdgcn_rcpf(x); }
__device__ __forceinline__ float frsq(float x)   { return __builtin_amdgcn_rsqf(x); }
__device__ __forceinline__ float fsqrt_(float x) { return __builtin_amdgcn_sqrtf(x); }
#if __has_builtin(__builtin_amdgcn_logf)
__device__ __forceinline__ float flog2(float x)  { return __builtin_amdgcn_logf(x); }
#else
__device__ __forceinline__ float flog2(float x)  { return __log2f(x); }
#endif
#if __has_builtin(__builtin_amdgcn_exp2f)
__device__ __forceinline__ float fexp2(float x)  { return __builtin_amdgcn_exp2f(x); }
#else
__device__ __forceinline__ float fexp2(float x)  { return exp2f(x); }
#endif

__global__ __launch_bounds__(256) void mann_elt_kernel(
        const float* __restrict__ k, float* __restrict__ out, int n_quads) {
    int tid = blockIdx.x * blockDim.x + threadIdx.x;
    if (tid >= n_quads) return;

    // 4 elements per thread: 12 contiguous floats = 3 float4 loads, all bytes
    // used (lines re-touched across the 3 loads hit in L1).
    const float4* __restrict__ k4 = (const float4*)k;
    float4 v0 = k4[3*tid+0];
    float4 v1 = k4[3*tid+1];
    float4 v2 = k4[3*tid+2];

    const float LS2 = 0.3481f;  // 0.59^2
    float q[4];
    q[0] = LS2 * (v0.x*v0.x + v0.y*v0.y + v0.z*v0.z);
    q[1] = LS2 * (v0.w*v0.w + v1.x*v1.x + v1.y*v1.y);
    q[2] = LS2 * (v1.z*v1.z + v1.w*v1.w + v2.x*v2.x);
    q[3] = LS2 * (v2.y*v2.y + v2.z*v2.z + v2.w*v2.w);

    bool brA[4];
    float z[4], acc[4], rr[4];
    #pragma unroll
    for (int e = 0; e < 4; ++e) {
        brA[e] = q[e] >= 0.6180339887f;      // t = 1/q <= phi
        rr[e] = frcp(1.0f + q[e]);           // = t/(1+t), series arg for branch A
        z[e] = brA[e] ? rr[e] : -q[e];
        acc[e] = 1.0f;
    }

    // Unified Horner; coefficients are compile-time literals, per-lane selected
    // (v_cndmask) -> no divergent loop; 4 independent dependency chains.
    #pragma unroll
    for (int n = NT - 1; n >= 0; --n) {
        const float cA = coefA(n);
        const float cB = coefB(n);
        #pragma unroll
        for (int e = 0; e < 4; ++e) {
            float c = brA[e] ? cA : cB;
            acc[e] = fmaf(c * z[e], acc[e], 1.0f);
        }
    }

    float res[4];
    #pragma unroll
    for (int e = 0; e < 4; ++e) {
        float qq = q[e];
        float S  = acc[e];
        // Branch A: arg = q * r^(1/3) * S   (r^(1/3) via native log2/exp2)
        float cr   = fexp2(flog2(rr[e]) * (1.0f/3.0f));
        float argA = qq * cr * S;
        // Branch B: arg = A*q + B*q^3*sqrt(q)*S   (no log/exp needed)
        float q72  = qq * qq * qq * fsqrt_(qq);
        float argB = fmaf((-2.0f/15.0f) * q72, S, 0.68834394f * qq);
        float arg  = brA[e] ? argA : argB;
        res[e] = 3.9f * frsq(arg);
    }

    // Non-temporal store: output is write-once, never re-read by us.
    nfloat4 r;
    r.x = res[0]; r.y = res[1]; r.z = res[2]; r.w = res[3];
    __builtin_nontemporal_store(r, (nfloat4*)out + tid);
}

extern "C" void kernel_launch(void* const* d_in, const int* in_sizes, int n_in,
                              void* d_out, int out_size, void* d_ws, size_t ws_size,
                              hipStream_t stream) {
    const float* k = (const float*)d_in[0];
    float* out = (float*)d_out;
    int n_quads = out_size / 4;                 // 16,777,216 / 4 = 4,194,304
    int threads = 256;
    int blocks = (n_quads + threads - 1) / threads;  // 16384
    mann_elt_kernel<<<blocks, threads, 0, stream>>>(k, out, n_quads);
}